// Round 20
// baseline (62.580 us; speedup 1.0000x reference)
//
#include <hip/hip_runtime.h>
#include <hip/hip_fp16.h>
#include <hip/hip_bf16.h>
#include <math.h>

#define BB   4
#define NN   1024
#define HIDD 256
#define NHD  8
#define DHD  32
#define BHD  64
#define TI2  2048          // table intervals over t in [-1,1], nearest-neighbor
#define TBSX 3592          // per-head table stride (ushorts): 2049 MLP + mask tail
#define NSPL 2             // kv-split factor
#define LOG2E 1.4426950408889634f

typedef __attribute__((ext_vector_type(8))) short bf16x8;
typedef __attribute__((ext_vector_type(4))) short bf16x4;
typedef __attribute__((ext_vector_type(4))) float f32x4;

// hardware bf16 convert (compiler maps to v_cvt)
__device__ __forceinline__ unsigned short f2bf(float x) {
  union { __hip_bfloat16 h; unsigned short u; } c;
  c.h = __float2bfloat16(x);
  return c.u;
}
__device__ __forceinline__ float bf2f(unsigned short b) {
  union { unsigned u; float f; } c; c.u = ((unsigned)b) << 16;
  return c.f;
}

// PV micro-op: oacc += A(V^T frag) . B(P^T frag), 16x16x16 bf16.
__device__ __forceinline__ void pv_mfma(f32x4& acc, bf16x4 a, bf16x4 b) {
#if __has_builtin(__builtin_amdgcn_mfma_f32_16x16x16bf16_1k)
  acc = __builtin_amdgcn_mfma_f32_16x16x16bf16_1k(a, b, acc, 0, 0, 0);
#else
  asm volatile("s_nop 1\n\t"
               "v_mfma_f32_16x16x16_bf16 %0, %1, %2, %0\n\t"
               "s_nop 7\n\t"
               "s_nop 3"
               : "+v"(acc) : "v"(a), "v"(b));
#endif
}

// ---- Kernel 1: prep = both weight transposes only --------------------------
// blocks [0,768)    : Wqkv [256][768] -> wtq bf16 [768][256]
// blocks [768,1024) : Wproj [256][256] -> wtp bf16 [256][256]
__global__ __launch_bounds__(256) void prep_kernel(
    const float* __restrict__ Wqkv, const float* __restrict__ Wproj,
    unsigned short* __restrict__ wtq, unsigned short* __restrict__ wtp)
{
  __shared__ float t[16][17];
  int bid = blockIdx.x, tid = threadIdx.x;
  const float* W; unsigned short* Wt; int n0, k0, ncols;
  if (bid < 768) {
    n0 = (bid % 48) * 16; k0 = (bid / 48) * 16; ncols = 768;
    W = Wqkv; Wt = wtq;
  } else {
    int rc = bid - 768;
    n0 = (rc & 15) * 16; k0 = (rc >> 4) * 16; ncols = 256;
    W = Wproj; Wt = wtp;
  }
  int sx = tid & 15, sy = tid >> 4;
  t[sy][sx] = W[(size_t)(k0 + sy) * ncols + n0 + sx];
  __syncthreads();
  Wt[(size_t)(n0 + sy) * 256 + k0 + sx] = f2bf(t[sx][sy]);
}

// ---- Kernel 2: fused LayerNorm + MFMA QKV GEMM + bias-table build ----------
// grid (256, 7): y<6 = LN+GEMM (r13 shape); y==6 = bias-table MLP blocks
// (table is consumed only by attn, which launches after this kernel).
__global__ __launch_bounds__(256) void ln_qkv_mm_kernel(
    const float* __restrict__ h, const float* __restrict__ gamma,
    const float* __restrict__ beta, const unsigned short* __restrict__ Wt,
    const float* __restrict__ bqkv,
    const float* __restrict__ Wb1, const float* __restrict__ bb1,
    const float* __restrict__ Wb2, const float* __restrict__ bb2,
    const float* __restrict__ Wb3, const float* __restrict__ bb3,
    unsigned short* __restrict__ tblb,
    unsigned short* __restrict__ qws, unsigned short* __restrict__ kws,
    unsigned short* __restrict__ vtws)
{
  __shared__ unsigned short xs[16][260];    // pad 4: row stride 130 dw
  __shared__ float th1[4][64], th2[4][64];
  int tid = threadIdx.x;

  if (blockIdx.y == 6) {                     // ---- bias-table blocks ----
    int x = blockIdx.x;                      // 0..255, 8 pts each (+pt 2048 @x=0)
    int g = tid >> 6, j = tid & 63;
    int npass = (x == 0) ? 3 : 2;
    for (int ps = 0; ps < npass; ++ps) {
      int pt = (ps < 2) ? (x*8 + ps*4 + g) : TI2;
      float tt = -1.0f + (float)pt * (2.0f / (float)TI2);
      float z0 = fmaf(tt, Wb1[j], bb1[j]);
      th1[g][j] = z0 / (1.0f + __expf(-z0));
      __syncthreads();
      float a0 = bb2[j];
      #pragma unroll 16
      for (int i = 0; i < BHD; ++i) a0 = fmaf(th1[g][i], Wb2[i*BHD + j], a0);
      th2[g][j] = a0 / (1.0f + __expf(-a0));
      __syncthreads();
      if (j < NHD) {
        float o0 = bb3[j];
        #pragma unroll 16
        for (int i = 0; i < BHD; ++i) o0 = fmaf(th2[g][i], Wb3[i*NHD + j], o0);
        tblb[j*TBSX + pt] = f2bf(o0 * LOG2E);  // log2 units
      }
      __syncthreads();                        // th1/th2 reuse next pass
    }
    if (x < NHD) {                            // tail fill: head x
      unsigned short neg = f2bf(-1e31f);
      for (int i = tid; i < TBSX - (TI2 + 1); i += 256)
        tblb[x*TBSX + TI2 + 1 + i] = neg;
    }
    return;
  }

  // ---- LN + GEMM path (r13 shape) ----
  int m0 = blockIdx.x * 16, n0 = blockIdx.y * 128;
  {
    int r = tid >> 4, q = tid & 15;
    const float* hrow = h + (size_t)(m0 + r)*HIDD + q*16;
    float4 xv[4];
    float sum = 0.f, sq = 0.f;
    #pragma unroll
    for (int j = 0; j < 4; ++j) {
      xv[j] = *(const float4*)&hrow[j*4];
      sum += xv[j].x + xv[j].y + xv[j].z + xv[j].w;
      sq  += xv[j].x*xv[j].x + xv[j].y*xv[j].y + xv[j].z*xv[j].z + xv[j].w*xv[j].w;
    }
    sum += __shfl_xor(sum, 1); sq += __shfl_xor(sq, 1);
    sum += __shfl_xor(sum, 2); sq += __shfl_xor(sq, 2);
    sum += __shfl_xor(sum, 4); sq += __shfl_xor(sq, 4);
    sum += __shfl_xor(sum, 8); sq += __shfl_xor(sq, 8);
    float mu  = sum * (1.0f/HIDD);
    float var = sq  * (1.0f/HIDD) - mu*mu;
    float rs  = rsqrtf(var + 1e-5f);
    #pragma unroll
    for (int j2 = 0; j2 < 2; ++j2) {
      union { bf16x8 v; unsigned short u[8]; } o;
      #pragma unroll
      for (int e = 0; e < 2; ++e) {
        float4 x4 = xv[j2*2 + e];
        int col = q*16 + j2*8 + e*4;
        float4 gv = *(const float4*)&gamma[col];
        float4 bv = *(const float4*)&beta[col];
        o.u[e*4+0] = f2bf(fmaf((x4.x - mu)*rs, gv.x, bv.x));
        o.u[e*4+1] = f2bf(fmaf((x4.y - mu)*rs, gv.y, bv.y));
        o.u[e*4+2] = f2bf(fmaf((x4.z - mu)*rs, gv.z, bv.z));
        o.u[e*4+3] = f2bf(fmaf((x4.w - mu)*rs, gv.w, bv.w));
      }
      *(bf16x8*)&xs[r][q*16 + j2*8] = o.v;
    }
  }
  __syncthreads();

  int lane = tid & 63, w = tid >> 6;
  int lo = lane & 15, hi = lane >> 4;
  int cw = w * 32;
  f32x4 acc[2];
  acc[0] = (f32x4){0.f,0.f,0.f,0.f};
  acc[1] = (f32x4){0.f,0.f,0.f,0.f};

  #pragma unroll
  for (int ks = 0; ks < 8; ++ks) {
    bf16x8 af = *(const bf16x8*)&xs[lo][ks*32 + hi*8];
    #pragma unroll
    for (int nt = 0; nt < 2; ++nt) {
      bf16x8 bf = *(const bf16x8*)&Wt[(size_t)(n0 + cw + nt*16 + lo)*256 + ks*32 + hi*8];
      acc[nt] = __builtin_amdgcn_mfma_f32_16x16x32_bf16(af, bf, acc[nt], 0, 0, 0);
    }
  }

  int b = m0 >> 10;
  if (n0 < 512) {
    unsigned short* dst = (n0 < 256) ? qws : kws;
    int nbase = (m0 & 1023) + hi*4;
    #pragma unroll
    for (int nt = 0; nt < 2; ++nt) {
      int c = n0 + cw + nt*16 + lo;
      int cr = c & 255;
      int head = cr >> 5, d = cr & 31;
      float bq = bqkv[c];
      size_t bh = (size_t)(b*NHD + head);
      #pragma unroll
      for (int r = 0; r < 4; ++r)
        dst[(bh*NN + nbase + r)*DHD + d] = f2bf(acc[nt][r] + bq);
    }
  } else {
    __syncthreads();
    unsigned short (*vt)[20] = (unsigned short(*)[20])&xs[0][0];  // [128][20]
    #pragma unroll
    for (int nt = 0; nt < 2; ++nt) {
      int cr = cw + nt*16 + lo;
      float bq = bqkv[n0 + cr];
      union { unsigned short u[4]; unsigned wd[2]; } pk;
      #pragma unroll
      for (int r = 0; r < 4; ++r) pk.u[r] = f2bf(acc[nt][r] + bq);
      int col = hi*4;
      *(unsigned*)&vt[cr][col]     = pk.wd[0];
      *(unsigned*)&vt[cr][col + 2] = pk.wd[1];
    }
    __syncthreads();
    int nn0 = m0 & 1023;
    int row = tid >> 1, ch = tid & 1;
    int cr256 = (n0 - 512) + row;
    int head = cr256 >> 5, d = cr256 & 31;
    *(bf16x8*)&vtws[((size_t)(b*NHD + head)*DHD + d)*NN + nn0 + ch*8] =
        *(const bf16x8*)&vt[row][ch*8];
  }
}

// ------- Kernel 3: swapped-operand MFMA flash attention, no-max softmax -----
// ckL pre-scaled by 1024 (exact); +1024 offset and +0.5 rounding folded into
// qoff2 -> index chain is {add, cvt, ds_read, shift, fmaf, exp2}. Masked keys
// (ck'=2560..3584) hit the -1e31 table tail -> exp2 -> exactly 0.
__global__ __launch_bounds__(256, 4) void attn_kernel(
    const unsigned short* __restrict__ Q, const unsigned short* __restrict__ K,
    const unsigned short* __restrict__ Vt, const float* __restrict__ coord,
    const int* __restrict__ mask, const unsigned short* __restrict__ tblb,
    unsigned short* __restrict__ pO, float* __restrict__ pL)
{
  __shared__ unsigned short tableL[TBSX];          // 7184 B (bf16, log2 units)
  __shared__ unsigned short Klds[2][64][40];       // 10 KB (dbuf)
  __shared__ unsigned short Vtlds[2][32][72];      //  9 KB (dbuf)
  __shared__ __align__(16) float ckL[NN/NSPL];     //  2 KB (pre-scaled coords)

  int tid = threadIdx.x, lane = tid & 63, w = tid >> 6;
  int bh = blockIdx.y, half = blockIdx.z;
  int b = bh >> 3, head = bh & 7;
  int qbase = blockIdx.x * 64 + w * 16;
  int lo = lane & 15, hi = lane >> 4;

  {
    const uint4* src = (const uint4*)(tblb + head*TBSX);
    uint4* dst = (uint4*)tableL;
    for (int i = tid; i < TBSX/8; i += 256) dst[i] = src[i];
  }

  bf16x8 qf = *(const bf16x8*)&Q[((size_t)bh*NN + qbase + lo)*DHD + hi*8];
  // i0 = (int)(ck*1024 + (1024.5 - cq*1024))
  float qoff2 = fmaf(coord[b*NN + qbase + lo], -(float)TI2*0.5f,
                     (float)TI2*0.5f + 0.5f);

  float l = 0.f;
  f32x4 oacc[2];
  oacc[0] = (f32x4){0.f,0.f,0.f,0.f};
  oacc[1] = (f32x4){0.f,0.f,0.f,0.f};
  const float scale2 = 0.17677669529663689f * LOG2E;

  int kt0 = half * (NN/NSPL);
  int sr = tid >> 2, ss = tid & 3;                 // K stage map
  int vr = tid >> 3, vs = tid & 7;                 // V stage map
  {
    #pragma unroll
    for (int i = 0; i < (NN/NSPL)/256; ++i) {
      int idx = i*256 + tid;
      // fold mask at stage time; pre-scale by 1024 (exact pow2 multiply)
      ckL[idx] = (mask[b*NN + kt0 + idx] ? coord[b*NN + kt0 + idx] : 2.5f)
                 * ((float)TI2*0.5f);
    }
    *(bf16x8*)&Klds[0][sr][ss*8] =
        *(const bf16x8*)&K[((size_t)bh*NN + kt0 + sr)*DHD + ss*8];
    *(bf16x8*)&Vtlds[0][vr][vs*8] =
        *(const bf16x8*)&Vt[((size_t)bh*DHD + vr)*NN + kt0 + vs*8];
  }
  __syncthreads();

  for (int t = 0; t < NN/NSPL/64; ++t) {
    int kt = kt0 + t*64;
    int cur = t & 1;
    bf16x8 kn, vn;
    if (t < NN/NSPL/64 - 1) {
      kn = *(const bf16x8*)&K[((size_t)bh*NN + kt + 64 + sr)*DHD + ss*8];
      vn = *(const bf16x8*)&Vt[((size_t)bh*DHD + vr)*NN + kt + 64 + vs*8];
    }
    // per-lane pre-scaled coords: LDS broadcast reads
    float ck[4][4];
    #pragma unroll
    for (int nt = 0; nt < 4; ++nt) {
      float4 c4 = *(const float4*)&ckL[t*64 + nt*16 + hi*4];
      ck[nt][0] = c4.x; ck[nt][1] = c4.y; ck[nt][2] = c4.z; ck[nt][3] = c4.w;
    }

    // S^T = K . Q^T
    f32x4 z = {0.f,0.f,0.f,0.f};
    f32x4 sacc[4];
    __builtin_amdgcn_s_setprio(1);
    #pragma unroll
    for (int nt = 0; nt < 4; ++nt) {
      bf16x8 kf = *(const bf16x8*)&Klds[cur][nt*16 + lo][hi*8];
      sacc[nt] = __builtin_amdgcn_mfma_f32_16x16x32_bf16(kf, qf, z, 0, 0, 0);
    }
    __builtin_amdgcn_s_setprio(0);

    // bias+mask lookup (nearest, log2 domain), then P = 2^s directly
    bf16x4 pfrag[4];
    #pragma unroll
    for (int nt = 0; nt < 4; ++nt) {
      float p[4];
      #pragma unroll
      for (int r = 0; r < 4; ++r) {
        int i0 = (int)(ck[nt][r] + qoff2);
        float s = fmaf(sacc[nt][r], scale2, bf2f(tableL[i0]));
        p[r] = __builtin_amdgcn_exp2f(s);
      }
      l += (p[0] + p[1]) + (p[2] + p[3]);
      union { bf16x4 v; unsigned short u[4]; } pk;
      pk.u[0] = f2bf(p[0]); pk.u[1] = f2bf(p[1]);
      pk.u[2] = f2bf(p[2]); pk.u[3] = f2bf(p[3]);
      pfrag[nt] = pk.v;
    }

    // O^T += V^T . P^T
    __builtin_amdgcn_s_setprio(1);
    #pragma unroll
    for (int nt = 0; nt < 4; ++nt) {
      #pragma unroll
      for (int n2 = 0; n2 < 2; ++n2) {
        bf16x4 vf = *(const bf16x4*)&Vtlds[cur][n2*16 + lo][nt*16 + hi*4];
        pv_mfma(oacc[n2], vf, pfrag[nt]);
      }
    }
    __builtin_amdgcn_s_setprio(0);

    if (t < NN/NSPL/64 - 1) {
      *(bf16x8*)&Klds[cur^1][sr][ss*8] = kn;
      *(bf16x8*)&Vtlds[cur^1][vr][vs*8] = vn;
    }
    __syncthreads();
  }

  // epilogue: l across hi-lanes; store unnormalized O^T (bf16) + l
  l += __shfl_xor(l, 16);
  l += __shfl_xor(l, 32);
  size_t base = ((size_t)(half*BB*NHD + bh)*NN + qbase + lo);
  #pragma unroll
  for (int n2 = 0; n2 < 2; ++n2) {
    union { bf16x4 v; unsigned short u[4]; } ov;
    ov.u[0] = f2bf(oacc[n2][0]); ov.u[1] = f2bf(oacc[n2][1]);
    ov.u[2] = f2bf(oacc[n2][2]); ov.u[3] = f2bf(oacc[n2][3]);
    *(bf16x4*)&pO[base*DHD + n2*16 + hi*4] = ov.v;
  }
  if (hi == 0) pL[base] = l;
}

// ---- Kernel 4: fused combine + MFMA proj GEMM + bias + residual ------------
// No-max softmax => merge is a pure add-and-scale: O = (O0 + O1)/(l0 + l1).
__global__ __launch_bounds__(256) void proj_mm_kernel(
    const unsigned short* __restrict__ pO, const float* __restrict__ pL,
    const unsigned short* __restrict__ Wpt, const float* __restrict__ bp,
    const float* __restrict__ h, float* __restrict__ out)
{
  __shared__ unsigned short alds[32][264];   // merged A-tile, +8 pad
  int tid = threadIdx.x;
  int m0 = blockIdx.x * 32, n0 = blockIdx.y * 32;

  // merge rows m0..m0+31: thread -> (row r, head q)
  {
    int r = tid >> 3, q = tid & 7;
    int g = m0 + r, b = g >> 10, n = g & 1023;
    int bhh = b*NHD + q;
    float l0 = pL[(size_t)bhh*NN + n];
    float l1 = pL[(size_t)(BB*NHD)*NN + (size_t)bhh*NN + n];
    float inv = 1.0f / (l0 + l1);
    const bf16x8* p0 = (const bf16x8*)&pO[((size_t)bhh*NN + n)*DHD];
    const bf16x8* p1 = (const bf16x8*)&pO[(((size_t)(BB*NHD) + bhh)*NN + n)*DHD];
    #pragma unroll
    for (int j = 0; j < 4; ++j) {
      union { bf16x8 v; unsigned short u[8]; } a, c, o;
      a.v = p0[j]; c.v = p1[j];
      #pragma unroll
      for (int e = 0; e < 8; ++e)
        o.u[e] = f2bf((bf2f(a.u[e]) + bf2f(c.u[e])) * inv);
      *(bf16x8*)&alds[r][q*32 + j*8] = o.v;
    }
  }
  __syncthreads();

  // GEMM: wave w -> rows m0+(w&1)*16, cols n0+(w>>1)*16
  int lane = tid & 63, w = tid >> 6;
  int lo = lane & 15, hi = lane >> 4;
  int mw = (w & 1) * 16;
  int nw = n0 + (w >> 1) * 16;
  f32x4 acc = (f32x4){0.f,0.f,0.f,0.f};

  #pragma unroll
  for (int ks = 0; ks < 8; ++ks) {
    bf16x8 af = *(const bf16x8*)&alds[mw + lo][ks*32 + hi*8];
    bf16x8 bf = *(const bf16x8*)&Wpt[(size_t)(nw + lo)*256 + ks*32 + hi*8];
    acc = __builtin_amdgcn_mfma_f32_16x16x32_bf16(af, bf, acc, 0, 0, 0);
  }

  int c = nw + lo;
  float bpv = bp[c];
  #pragma unroll
  for (int r = 0; r < 4; ++r) {
    size_t o = (size_t)(m0 + mw + hi*4 + r)*HIDD + c;
    out[o] = h[o] + acc[r] + bpv;
  }
}

// ---------------- launch ----------------------------------------------------
extern "C" void kernel_launch(void* const* d_in, const int* in_sizes, int n_in,
                              void* d_out, int out_size, void* d_ws, size_t ws_size,
                              hipStream_t stream)
{
  const float* h     = (const float*)d_in[0];
  const float* coord = (const float*)d_in[1];
  const int*   mask  = (const int*)  d_in[2];
  const float* Wqkv  = (const float*)d_in[3];
  const float* bqkv  = (const float*)d_in[4];
  const float* Wproj = (const float*)d_in[5];
  const float* bproj = (const float*)d_in[6];
  const float* gamma = (const float*)d_in[7];
  const float* beta  = (const float*)d_in[8];
  const float* Wb1   = (const float*)d_in[9];
  const float* bb1   = (const float*)d_in[10];
  const float* Wb2   = (const float*)d_in[11];
  const float* bb2   = (const float*)d_in[12];
  const float* Wb3   = (const float*)d_in[13];
  const float* bb3   = (const float*)d_in[14];
  float* out = (float*)d_out;

  unsigned short* tblb = (unsigned short*)d_ws;         // 8*3592 ushorts (57472 B)
  float* pL = (float*)(tblb + NHD*TBSX);                // 64K floats (256 KB)
  unsigned short* wtq  = (unsigned short*)(pL + (size_t)NSPL*BB*NHD*NN);
  unsigned short* wtp  = wtq + 768*256;
  unsigned short* qws  = wtp + 256*256;
  unsigned short* kws  = qws + (size_t)BB*NHD*NN*DHD;   // 1 Mi elems each
  unsigned short* vtws = kws + (size_t)BB*NHD*NN*DHD;
  unsigned short* pO   = vtws + (size_t)BB*NHD*NN*DHD;  // 2 Mi elems (bf16)

  prep_kernel<<<dim3(1024), dim3(256), 0, stream>>>(Wqkv, Wproj, wtq, wtp);
  ln_qkv_mm_kernel<<<dim3(BB*NN/16, 7), dim3(256), 0, stream>>>(
      h, gamma, beta, wtq, bqkv, Wb1, bb1, Wb2, bb2, Wb3, bb3, tblb,
      qws, kws, vtws);
  attn_kernel<<<dim3(NN/64, BB*NHD, NSPL), dim3(256), 0, stream>>>(
      qws, kws, vtws, coord, mask, tblb, pO, pL);
  proj_mm_kernel<<<dim3(BB*NN/32, HIDD/32), dim3(256), 0, stream>>>(
      pO, pL, wtp, bproj, h, out);
}

// Round 21
// 59.289 us; speedup vs baseline: 1.0555x; 1.0555x over previous
//
#include <hip/hip_runtime.h>
#include <hip/hip_fp16.h>
#include <hip/hip_bf16.h>
#include <math.h>

#define BB   4
#define NN   1024
#define HIDD 256
#define NHD  8
#define DHD  32
#define BHD  64
#define TI2  2048          // table intervals over t in [-1,1], nearest-neighbor
#define TBSX 3592          // per-head table stride (ushorts): 2049 MLP + mask tail
#define NSPL 2             // kv-split factor
#define LOG2E 1.4426950408889634f

typedef __attribute__((ext_vector_type(8))) short bf16x8;
typedef __attribute__((ext_vector_type(4))) short bf16x4;
typedef __attribute__((ext_vector_type(4))) float f32x4;

// hardware bf16 convert (compiler maps to v_cvt)
__device__ __forceinline__ unsigned short f2bf(float x) {
  union { __hip_bfloat16 h; unsigned short u; } c;
  c.h = __float2bfloat16(x);
  return c.u;
}
__device__ __forceinline__ float bf2f(unsigned short b) {
  union { unsigned u; float f; } c; c.u = ((unsigned)b) << 16;
  return c.f;
}

// PV micro-op: oacc += A(V^T frag) . B(P^T frag), 16x16x16 bf16.
__device__ __forceinline__ void pv_mfma(f32x4& acc, bf16x4 a, bf16x4 b) {
#if __has_builtin(__builtin_amdgcn_mfma_f32_16x16x16bf16_1k)
  acc = __builtin_amdgcn_mfma_f32_16x16x16bf16_1k(a, b, acc, 0, 0, 0);
#else
  asm volatile("s_nop 1\n\t"
               "v_mfma_f32_16x16x16_bf16 %0, %1, %2, %0\n\t"
               "s_nop 7\n\t"
               "s_nop 3"
               : "+v"(acc) : "v"(a), "v"(b));
#endif
}

// ---- Kernel 1: prep = bias-table + mask tail + both weight transposes ------
__global__ __launch_bounds__(256) void prep_kernel(
    const float* __restrict__ Wb1, const float* __restrict__ bb1,
    const float* __restrict__ Wb2, const float* __restrict__ bb2,
    const float* __restrict__ Wb3, const float* __restrict__ bb3,
    const float* __restrict__ Wqkv, const float* __restrict__ Wproj,
    unsigned short* __restrict__ tblb, unsigned short* __restrict__ wtq,
    unsigned short* __restrict__ wtp)
{
  __shared__ float h1a[4][64], h2a[4][64];
  __shared__ float t[16][17];
  int bid = blockIdx.x, tid = threadIdx.x;
  if (bid < 513) {
    int g = tid >> 6, j = tid & 63;
    int pt = bid * 4 + g;                          // 0..2051
    float tt = -1.0f + (float)pt * (2.0f / (float)TI2);
    float z0 = fmaf(tt, Wb1[j], bb1[j]);
    h1a[g][j] = z0 / (1.0f + __expf(-z0));
    __syncthreads();
    float a0 = bb2[j];
    #pragma unroll 16
    for (int i = 0; i < BHD; ++i) a0 = fmaf(h1a[g][i], Wb2[i*BHD + j], a0);
    h2a[g][j] = a0 / (1.0f + __expf(-a0));
    __syncthreads();
    if (j < NHD && pt <= TI2) {
      float o0 = bb3[j];
      #pragma unroll 16
      for (int i = 0; i < BHD; ++i) o0 = fmaf(h2a[g][i], Wb3[i*NHD + j], o0);
      tblb[j*TBSX + pt] = f2bf(o0 * LOG2E);        // log2 units
    }
  } else if (bid < 521) {
    int head = bid - 513;
    unsigned short neg = f2bf(-1e31f);
    for (int i = tid; i < TBSX - (TI2 + 1); i += 256)
      tblb[head*TBSX + TI2 + 1 + i] = neg;
  } else {
    const float* W; unsigned short* Wt; int n0, k0, ncols;
    if (bid < 1289) {
      int rb = bid - 521;                 // 768 blocks: 48 x 16
      n0 = (rb % 48) * 16; k0 = (rb / 48) * 16; ncols = 768;
      W = Wqkv; Wt = wtq;
    } else {
      int rc = bid - 1289;                // 256 blocks: 16 x 16
      n0 = (rc & 15) * 16; k0 = (rc >> 4) * 16; ncols = 256;
      W = Wproj; Wt = wtp;
    }
    int sx = tid & 15, sy = tid >> 4;
    t[sy][sx] = W[(size_t)(k0 + sy) * ncols + n0 + sx];
    __syncthreads();
    Wt[(size_t)(n0 + sy) * 256 + k0 + sx] = f2bf(t[sx][sy]);
  }
}

// ---- Kernel 2: fused LayerNorm + MFMA QKV GEMM, 16 rows/block (r13) --------
__global__ __launch_bounds__(256) void ln_qkv_mm_kernel(
    const float* __restrict__ h, const float* __restrict__ gamma,
    const float* __restrict__ beta, const unsigned short* __restrict__ Wt,
    const float* __restrict__ bqkv,
    unsigned short* __restrict__ qws, unsigned short* __restrict__ kws,
    unsigned short* __restrict__ vtws)
{
  __shared__ unsigned short xs[16][260];    // pad 4: row stride 130 dw = 2 mod 32
  int tid = threadIdx.x;
  int m0 = blockIdx.x * 16, n0 = blockIdx.y * 128;

  {
    int r = tid >> 4, q = tid & 15;
    const float* hrow = h + (size_t)(m0 + r)*HIDD + q*16;
    float4 xv[4];
    float sum = 0.f, sq = 0.f;
    #pragma unroll
    for (int j = 0; j < 4; ++j) {
      xv[j] = *(const float4*)&hrow[j*4];
      sum += xv[j].x + xv[j].y + xv[j].z + xv[j].w;
      sq  += xv[j].x*xv[j].x + xv[j].y*xv[j].y + xv[j].z*xv[j].z + xv[j].w*xv[j].w;
    }
    sum += __shfl_xor(sum, 1); sq += __shfl_xor(sq, 1);
    sum += __shfl_xor(sum, 2); sq += __shfl_xor(sq, 2);
    sum += __shfl_xor(sum, 4); sq += __shfl_xor(sq, 4);
    sum += __shfl_xor(sum, 8); sq += __shfl_xor(sq, 8);
    float mu  = sum * (1.0f/HIDD);
    float var = sq  * (1.0f/HIDD) - mu*mu;
    float rs  = rsqrtf(var + 1e-5f);
    #pragma unroll
    for (int j2 = 0; j2 < 2; ++j2) {
      union { bf16x8 v; unsigned short u[8]; } o;
      #pragma unroll
      for (int e = 0; e < 2; ++e) {
        float4 x4 = xv[j2*2 + e];
        int col = q*16 + j2*8 + e*4;
        float4 gv = *(const float4*)&gamma[col];
        float4 bv = *(const float4*)&beta[col];
        o.u[e*4+0] = f2bf(fmaf((x4.x - mu)*rs, gv.x, bv.x));
        o.u[e*4+1] = f2bf(fmaf((x4.y - mu)*rs, gv.y, bv.y));
        o.u[e*4+2] = f2bf(fmaf((x4.z - mu)*rs, gv.z, bv.z));
        o.u[e*4+3] = f2bf(fmaf((x4.w - mu)*rs, gv.w, bv.w));
      }
      *(bf16x8*)&xs[r][q*16 + j2*8] = o.v;
    }
  }
  __syncthreads();

  int lane = tid & 63, w = tid >> 6;
  int lo = lane & 15, hi = lane >> 4;
  int cw = w * 32;
  f32x4 acc[2];
  acc[0] = (f32x4){0.f,0.f,0.f,0.f};
  acc[1] = (f32x4){0.f,0.f,0.f,0.f};

  #pragma unroll
  for (int ks = 0; ks < 8; ++ks) {
    bf16x8 af = *(const bf16x8*)&xs[lo][ks*32 + hi*8];
    #pragma unroll
    for (int nt = 0; nt < 2; ++nt) {
      bf16x8 bf = *(const bf16x8*)&Wt[(size_t)(n0 + cw + nt*16 + lo)*256 + ks*32 + hi*8];
      acc[nt] = __builtin_amdgcn_mfma_f32_16x16x32_bf16(af, bf, acc[nt], 0, 0, 0);
    }
  }

  int b = m0 >> 10;
  if (n0 < 512) {
    unsigned short* dst = (n0 < 256) ? qws : kws;
    int nbase = (m0 & 1023) + hi*4;
    #pragma unroll
    for (int nt = 0; nt < 2; ++nt) {
      int c = n0 + cw + nt*16 + lo;
      int cr = c & 255;
      int head = cr >> 5, d = cr & 31;
      float bq = bqkv[c];
      size_t bh = (size_t)(b*NHD + head);
      #pragma unroll
      for (int r = 0; r < 4; ++r)
        dst[(bh*NN + nbase + r)*DHD + d] = f2bf(acc[nt][r] + bq);
    }
  } else {
    __syncthreads();
    unsigned short (*vt)[20] = (unsigned short(*)[20])&xs[0][0];  // [128][20]
    #pragma unroll
    for (int nt = 0; nt < 2; ++nt) {
      int cr = cw + nt*16 + lo;
      float bq = bqkv[n0 + cr];
      union { unsigned short u[4]; unsigned wd[2]; } pk;
      #pragma unroll
      for (int r = 0; r < 4; ++r) pk.u[r] = f2bf(acc[nt][r] + bq);
      int col = hi*4;
      *(unsigned*)&vt[cr][col]     = pk.wd[0];
      *(unsigned*)&vt[cr][col + 2] = pk.wd[1];
    }
    __syncthreads();
    int nn0 = m0 & 1023;
    int row = tid >> 1, ch = tid & 1;
    int cr256 = (n0 - 512) + row;
    int head = cr256 >> 5, d = cr256 & 31;
    *(bf16x8*)&vtws[((size_t)(b*NHD + head)*DHD + d)*NN + nn0 + ch*8] =
        *(const bf16x8*)&vt[row][ch*8];
  }
}

// ------- Kernel 3: swapped-operand MFMA flash attention, no-max softmax -----
// ckL pre-scaled by 1024 (exact); +1024 offset and +0.5 rounding folded into
// qoff2 -> index chain is {add, cvt, ds_read, shift, fmaf, exp2}. Masked keys
// (ck'=2560) hit the -1e31 table tail -> exp2 -> exactly 0.
__global__ __launch_bounds__(256, 4) void attn_kernel(
    const unsigned short* __restrict__ Q, const unsigned short* __restrict__ K,
    const unsigned short* __restrict__ Vt, const float* __restrict__ coord,
    const int* __restrict__ mask, const unsigned short* __restrict__ tblb,
    unsigned short* __restrict__ pO, float* __restrict__ pL)
{
  __shared__ unsigned short tableL[TBSX];          // 7184 B (bf16, log2 units)
  __shared__ unsigned short Klds[2][64][40];       // 10 KB (dbuf)
  __shared__ unsigned short Vtlds[2][32][72];      //  9 KB (dbuf)
  __shared__ __align__(16) float ckL[NN/NSPL];     //  2 KB (pre-scaled coords)

  int tid = threadIdx.x, lane = tid & 63, w = tid >> 6;
  int bh = blockIdx.y, half = blockIdx.z;
  int b = bh >> 3, head = bh & 7;
  int qbase = blockIdx.x * 64 + w * 16;
  int lo = lane & 15, hi = lane >> 4;

  {
    const uint4* src = (const uint4*)(tblb + head*TBSX);
    uint4* dst = (uint4*)tableL;
    for (int i = tid; i < TBSX/8; i += 256) dst[i] = src[i];
  }

  bf16x8 qf = *(const bf16x8*)&Q[((size_t)bh*NN + qbase + lo)*DHD + hi*8];
  // i0 = (int)(ck*1024 + (1024.5 - cq*1024))
  float qoff2 = fmaf(coord[b*NN + qbase + lo], -(float)TI2*0.5f,
                     (float)TI2*0.5f + 0.5f);

  float l = 0.f;
  f32x4 oacc[2];
  oacc[0] = (f32x4){0.f,0.f,0.f,0.f};
  oacc[1] = (f32x4){0.f,0.f,0.f,0.f};
  const float scale2 = 0.17677669529663689f * LOG2E;

  int kt0 = half * (NN/NSPL);
  int sr = tid >> 2, ss = tid & 3;                 // K stage map
  int vr = tid >> 3, vs = tid & 7;                 // V stage map
  {
    #pragma unroll
    for (int i = 0; i < (NN/NSPL)/256; ++i) {
      int idx = i*256 + tid;
      // fold mask at stage time; pre-scale by 1024 (exact pow2 multiply)
      ckL[idx] = (mask[b*NN + kt0 + idx] ? coord[b*NN + kt0 + idx] : 2.5f)
                 * ((float)TI2*0.5f);
    }
    *(bf16x8*)&Klds[0][sr][ss*8] =
        *(const bf16x8*)&K[((size_t)bh*NN + kt0 + sr)*DHD + ss*8];
    *(bf16x8*)&Vtlds[0][vr][vs*8] =
        *(const bf16x8*)&Vt[((size_t)bh*DHD + vr)*NN + kt0 + vs*8];
  }
  __syncthreads();

  for (int t = 0; t < NN/NSPL/64; ++t) {
    int kt = kt0 + t*64;
    int cur = t & 1;
    bf16x8 kn, vn;
    if (t < NN/NSPL/64 - 1) {
      kn = *(const bf16x8*)&K[((size_t)bh*NN + kt + 64 + sr)*DHD + ss*8];
      vn = *(const bf16x8*)&Vt[((size_t)bh*DHD + vr)*NN + kt + 64 + vs*8];
    }
    // per-lane pre-scaled coords: LDS broadcast reads
    float ck[4][4];
    #pragma unroll
    for (int nt = 0; nt < 4; ++nt) {
      float4 c4 = *(const float4*)&ckL[t*64 + nt*16 + hi*4];
      ck[nt][0] = c4.x; ck[nt][1] = c4.y; ck[nt][2] = c4.z; ck[nt][3] = c4.w;
    }

    // S^T = K . Q^T
    f32x4 z = {0.f,0.f,0.f,0.f};
    f32x4 sacc[4];
    #pragma unroll
    for (int nt = 0; nt < 4; ++nt) {
      bf16x8 kf = *(const bf16x8*)&Klds[cur][nt*16 + lo][hi*8];
      sacc[nt] = __builtin_amdgcn_mfma_f32_16x16x32_bf16(kf, qf, z, 0, 0, 0);
    }

    // bias+mask lookup (nearest, log2 domain), then P = 2^s directly
    bf16x4 pfrag[4];
    #pragma unroll
    for (int nt = 0; nt < 4; ++nt) {
      float p[4];
      #pragma unroll
      for (int r = 0; r < 4; ++r) {
        int i0 = (int)(ck[nt][r] + qoff2);
        float s = fmaf(sacc[nt][r], scale2, bf2f(tableL[i0]));
        p[r] = __builtin_amdgcn_exp2f(s);
      }
      l += (p[0] + p[1]) + (p[2] + p[3]);
      union { bf16x4 v; unsigned short u[4]; } pk;
      pk.u[0] = f2bf(p[0]); pk.u[1] = f2bf(p[1]);
      pk.u[2] = f2bf(p[2]); pk.u[3] = f2bf(p[3]);
      pfrag[nt] = pk.v;
    }

    // O^T += V^T . P^T
    #pragma unroll
    for (int nt = 0; nt < 4; ++nt) {
      #pragma unroll
      for (int n2 = 0; n2 < 2; ++n2) {
        bf16x4 vf = *(const bf16x4*)&Vtlds[cur][n2*16 + lo][nt*16 + hi*4];
        pv_mfma(oacc[n2], vf, pfrag[nt]);
      }
    }

    if (t < NN/NSPL/64 - 1) {
      *(bf16x8*)&Klds[cur^1][sr][ss*8] = kn;
      *(bf16x8*)&Vtlds[cur^1][vr][vs*8] = vn;
    }
    __syncthreads();
  }

  // epilogue: l across hi-lanes; store unnormalized O^T (bf16) + l
  l += __shfl_xor(l, 16);
  l += __shfl_xor(l, 32);
  size_t base = ((size_t)(half*BB*NHD + bh)*NN + qbase + lo);
  #pragma unroll
  for (int n2 = 0; n2 < 2; ++n2) {
    union { bf16x4 v; unsigned short u[4]; } ov;
    ov.u[0] = f2bf(oacc[n2][0]); ov.u[1] = f2bf(oacc[n2][1]);
    ov.u[2] = f2bf(oacc[n2][2]); ov.u[3] = f2bf(oacc[n2][3]);
    *(bf16x4*)&pO[base*DHD + n2*16 + hi*4] = ov.v;
  }
  if (hi == 0) pL[base] = l;
}

// ---- Kernel 4: fused combine + MFMA proj GEMM + bias + residual ------------
// No-max softmax => merge is a pure add-and-scale: O = (O0 + O1)/(l0 + l1).
__global__ __launch_bounds__(256) void proj_mm_kernel(
    const unsigned short* __restrict__ pO, const float* __restrict__ pL,
    const unsigned short* __restrict__ Wpt, const float* __restrict__ bp,
    const float* __restrict__ h, float* __restrict__ out)
{
  __shared__ unsigned short alds[32][264];   // merged A-tile, +8 pad
  int tid = threadIdx.x;
  int m0 = blockIdx.x * 32, n0 = blockIdx.y * 32;

  // merge rows m0..m0+31: thread -> (row r, head q)
  {
    int r = tid >> 3, q = tid & 7;
    int g = m0 + r, b = g >> 10, n = g & 1023;
    int bhh = b*NHD + q;
    float l0 = pL[(size_t)bhh*NN + n];
    float l1 = pL[(size_t)(BB*NHD)*NN + (size_t)bhh*NN + n];
    float inv = 1.0f / (l0 + l1);
    const bf16x8* p0 = (const bf16x8*)&pO[((size_t)bhh*NN + n)*DHD];
    const bf16x8* p1 = (const bf16x8*)&pO[(((size_t)(BB*NHD) + bhh)*NN + n)*DHD];
    #pragma unroll
    for (int j = 0; j < 4; ++j) {
      union { bf16x8 v; unsigned short u[8]; } a, c, o;
      a.v = p0[j]; c.v = p1[j];
      #pragma unroll
      for (int e = 0; e < 8; ++e)
        o.u[e] = f2bf((bf2f(a.u[e]) + bf2f(c.u[e])) * inv);
      *(bf16x8*)&alds[r][q*32 + j*8] = o.v;
    }
  }
  __syncthreads();

  // GEMM: wave w -> rows m0+(w&1)*16, cols n0+(w>>1)*16
  int lane = tid & 63, w = tid >> 6;
  int lo = lane & 15, hi = lane >> 4;
  int mw = (w & 1) * 16;
  int nw = n0 + (w >> 1) * 16;
  f32x4 acc = (f32x4){0.f,0.f,0.f,0.f};

  #pragma unroll
  for (int ks = 0; ks < 8; ++ks) {
    bf16x8 af = *(const bf16x8*)&alds[mw + lo][ks*32 + hi*8];
    bf16x8 bf = *(const bf16x8*)&Wpt[(size_t)(nw + lo)*256 + ks*32 + hi*8];
    acc = __builtin_amdgcn_mfma_f32_16x16x32_bf16(af, bf, acc, 0, 0, 0);
  }

  int c = nw + lo;
  float bpv = bp[c];
  #pragma unroll
  for (int r = 0; r < 4; ++r) {
    size_t o = (size_t)(m0 + mw + hi*4 + r)*HIDD + c;
    out[o] = h[o] + acc[r] + bpv;
  }
}

// ---------------- launch ----------------------------------------------------
extern "C" void kernel_launch(void* const* d_in, const int* in_sizes, int n_in,
                              void* d_out, int out_size, void* d_ws, size_t ws_size,
                              hipStream_t stream)
{
  const float* h     = (const float*)d_in[0];
  const float* coord = (const float*)d_in[1];
  const int*   mask  = (const int*)  d_in[2];
  const float* Wqkv  = (const float*)d_in[3];
  const float* bqkv  = (const float*)d_in[4];
  const float* Wproj = (const float*)d_in[5];
  const float* bproj = (const float*)d_in[6];
  const float* gamma = (const float*)d_in[7];
  const float* beta  = (const float*)d_in[8];
  const float* Wb1   = (const float*)d_in[9];
  const float* bb1   = (const float*)d_in[10];
  const float* Wb2   = (const float*)d_in[11];
  const float* bb2   = (const float*)d_in[12];
  const float* Wb3   = (const float*)d_in[13];
  const float* bb3   = (const float*)d_in[14];
  float* out = (float*)d_out;

  unsigned short* tblb = (unsigned short*)d_ws;         // 8*3592 ushorts (57472 B)
  float* pL = (float*)(tblb + NHD*TBSX);                // 64K floats (256 KB)
  unsigned short* wtq  = (unsigned short*)(pL + (size_t)NSPL*BB*NHD*NN);
  unsigned short* wtp  = wtq + 768*256;
  unsigned short* qws  = wtp + 256*256;
  unsigned short* kws  = qws + (size_t)BB*NHD*NN*DHD;   // 1 Mi elems each
  unsigned short* vtws = kws + (size_t)BB*NHD*NN*DHD;
  unsigned short* pO   = vtws + (size_t)BB*NHD*NN*DHD;  // 2 Mi elems (bf16)

  prep_kernel<<<dim3(1545), dim3(256), 0, stream>>>(
      Wb1, bb1, Wb2, bb2, Wb3, bb3, Wqkv, Wproj, tblb, wtq, wtp);
  ln_qkv_mm_kernel<<<dim3(BB*NN/16, 6), dim3(256), 0, stream>>>(
      h, gamma, beta, wtq, bqkv, qws, kws, vtws);
  attn_kernel<<<dim3(NN/64, BB*NHD, NSPL), dim3(256), 0, stream>>>(
      qws, kws, vtws, coord, mask, tblb, pO, pL);
  proj_mm_kernel<<<dim3(BB*NN/32, HIDD/32), dim3(256), 0, stream>>>(
      pO, pL, wtp, bproj, h, out);
}

// Round 22
// 59.205 us; speedup vs baseline: 1.0570x; 1.0014x over previous
//
#include <hip/hip_runtime.h>
#include <hip/hip_fp16.h>
#include <hip/hip_bf16.h>
#include <math.h>

#define BB   4
#define NN   1024
#define HIDD 256
#define NHD  8
#define DHD  32
#define BHD  64
#define TI2  2048          // table intervals over t in [-1,1], nearest-neighbor
#define TBSX 3592          // per-head table stride (ushorts): 2049 MLP + mask tail
#define NSPL 2             // kv-split factor
#define LOG2E 1.4426950408889634f

typedef __attribute__((ext_vector_type(8))) short bf16x8;
typedef __attribute__((ext_vector_type(4))) short bf16x4;
typedef __attribute__((ext_vector_type(4))) float f32x4;

// hardware bf16 convert (compiler maps to v_cvt)
__device__ __forceinline__ unsigned short f2bf(float x) {
  union { __hip_bfloat16 h; unsigned short u; } c;
  c.h = __float2bfloat16(x);
  return c.u;
}
__device__ __forceinline__ float bf2f(unsigned short b) {
  union { unsigned u; float f; } c; c.u = ((unsigned)b) << 16;
  return c.f;
}

// PV micro-op: oacc += A(V^T frag) . B(P^T frag), 16x16x16 bf16.
__device__ __forceinline__ void pv_mfma(f32x4& acc, bf16x4 a, bf16x4 b) {
#if __has_builtin(__builtin_amdgcn_mfma_f32_16x16x16bf16_1k)
  acc = __builtin_amdgcn_mfma_f32_16x16x16bf16_1k(a, b, acc, 0, 0, 0);
#else
  asm volatile("s_nop 1\n\t"
               "v_mfma_f32_16x16x16_bf16 %0, %1, %2, %0\n\t"
               "s_nop 7\n\t"
               "s_nop 3"
               : "+v"(acc) : "v"(a), "v"(b));
#endif
}

// ---- Kernel 1: prep = bias-table + mask tail + both weight transposes ------
__global__ __launch_bounds__(256) void prep_kernel(
    const float* __restrict__ Wb1, const float* __restrict__ bb1,
    const float* __restrict__ Wb2, const float* __restrict__ bb2,
    const float* __restrict__ Wb3, const float* __restrict__ bb3,
    const float* __restrict__ Wqkv, const float* __restrict__ Wproj,
    unsigned short* __restrict__ tblb, unsigned short* __restrict__ wtq,
    unsigned short* __restrict__ wtp)
{
  __shared__ float h1a[4][64], h2a[4][64];
  __shared__ float t[16][17];
  int bid = blockIdx.x, tid = threadIdx.x;
  if (bid < 513) {
    int g = tid >> 6, j = tid & 63;
    int pt = bid * 4 + g;                          // 0..2051
    float tt = -1.0f + (float)pt * (2.0f / (float)TI2);
    float z0 = fmaf(tt, Wb1[j], bb1[j]);
    h1a[g][j] = z0 / (1.0f + __expf(-z0));
    __syncthreads();
    float a0 = bb2[j];
    #pragma unroll 16
    for (int i = 0; i < BHD; ++i) a0 = fmaf(h1a[g][i], Wb2[i*BHD + j], a0);
    h2a[g][j] = a0 / (1.0f + __expf(-a0));
    __syncthreads();
    if (j < NHD && pt <= TI2) {
      float o0 = bb3[j];
      #pragma unroll 16
      for (int i = 0; i < BHD; ++i) o0 = fmaf(h2a[g][i], Wb3[i*NHD + j], o0);
      tblb[j*TBSX + pt] = f2bf(o0 * LOG2E);        // log2 units
    }
  } else if (bid < 521) {
    int head = bid - 513;
    unsigned short neg = f2bf(-1e31f);
    for (int i = tid; i < TBSX - (TI2 + 1); i += 256)
      tblb[head*TBSX + TI2 + 1 + i] = neg;
  } else {
    const float* W; unsigned short* Wt; int n0, k0, ncols;
    if (bid < 1289) {
      int rb = bid - 521;                 // 768 blocks: 48 x 16
      n0 = (rb % 48) * 16; k0 = (rb / 48) * 16; ncols = 768;
      W = Wqkv; Wt = wtq;
    } else {
      int rc = bid - 1289;                // 256 blocks: 16 x 16
      n0 = (rc & 15) * 16; k0 = (rc >> 4) * 16; ncols = 256;
      W = Wproj; Wt = wtp;
    }
    int sx = tid & 15, sy = tid >> 4;
    t[sy][sx] = W[(size_t)(k0 + sy) * ncols + n0 + sx];
    __syncthreads();
    Wt[(size_t)(n0 + sy) * 256 + k0 + sx] = f2bf(t[sx][sy]);
  }
}

// ---- Kernel 2: fused LayerNorm + MFMA QKV GEMM, 16 rows/block (r13) --------
__global__ __launch_bounds__(256) void ln_qkv_mm_kernel(
    const float* __restrict__ h, const float* __restrict__ gamma,
    const float* __restrict__ beta, const unsigned short* __restrict__ Wt,
    const float* __restrict__ bqkv,
    unsigned short* __restrict__ qws, unsigned short* __restrict__ kws,
    unsigned short* __restrict__ vtws)
{
  __shared__ unsigned short xs[16][260];    // pad 4: row stride 130 dw = 2 mod 32
  int tid = threadIdx.x;
  int m0 = blockIdx.x * 16, n0 = blockIdx.y * 128;

  {
    int r = tid >> 4, q = tid & 15;
    const float* hrow = h + (size_t)(m0 + r)*HIDD + q*16;
    float4 xv[4];
    float sum = 0.f, sq = 0.f;
    #pragma unroll
    for (int j = 0; j < 4; ++j) {
      xv[j] = *(const float4*)&hrow[j*4];
      sum += xv[j].x + xv[j].y + xv[j].z + xv[j].w;
      sq  += xv[j].x*xv[j].x + xv[j].y*xv[j].y + xv[j].z*xv[j].z + xv[j].w*xv[j].w;
    }
    sum += __shfl_xor(sum, 1); sq += __shfl_xor(sq, 1);
    sum += __shfl_xor(sum, 2); sq += __shfl_xor(sq, 2);
    sum += __shfl_xor(sum, 4); sq += __shfl_xor(sq, 4);
    sum += __shfl_xor(sum, 8); sq += __shfl_xor(sq, 8);
    float mu  = sum * (1.0f/HIDD);
    float var = sq  * (1.0f/HIDD) - mu*mu;
    float rs  = rsqrtf(var + 1e-5f);
    #pragma unroll
    for (int j2 = 0; j2 < 2; ++j2) {
      union { bf16x8 v; unsigned short u[8]; } o;
      #pragma unroll
      for (int e = 0; e < 2; ++e) {
        float4 x4 = xv[j2*2 + e];
        int col = q*16 + j2*8 + e*4;
        float4 gv = *(const float4*)&gamma[col];
        float4 bv = *(const float4*)&beta[col];
        o.u[e*4+0] = f2bf(fmaf((x4.x - mu)*rs, gv.x, bv.x));
        o.u[e*4+1] = f2bf(fmaf((x4.y - mu)*rs, gv.y, bv.y));
        o.u[e*4+2] = f2bf(fmaf((x4.z - mu)*rs, gv.z, bv.z));
        o.u[e*4+3] = f2bf(fmaf((x4.w - mu)*rs, gv.w, bv.w));
      }
      *(bf16x8*)&xs[r][q*16 + j2*8] = o.v;
    }
  }
  __syncthreads();

  int lane = tid & 63, w = tid >> 6;
  int lo = lane & 15, hi = lane >> 4;
  int cw = w * 32;
  f32x4 acc[2];
  acc[0] = (f32x4){0.f,0.f,0.f,0.f};
  acc[1] = (f32x4){0.f,0.f,0.f,0.f};

  #pragma unroll
  for (int ks = 0; ks < 8; ++ks) {
    bf16x8 af = *(const bf16x8*)&xs[lo][ks*32 + hi*8];
    #pragma unroll
    for (int nt = 0; nt < 2; ++nt) {
      bf16x8 bf = *(const bf16x8*)&Wt[(size_t)(n0 + cw + nt*16 + lo)*256 + ks*32 + hi*8];
      acc[nt] = __builtin_amdgcn_mfma_f32_16x16x32_bf16(af, bf, acc[nt], 0, 0, 0);
    }
  }

  int b = m0 >> 10;
  if (n0 < 512) {
    unsigned short* dst = (n0 < 256) ? qws : kws;
    int nbase = (m0 & 1023) + hi*4;
    #pragma unroll
    for (int nt = 0; nt < 2; ++nt) {
      int c = n0 + cw + nt*16 + lo;
      int cr = c & 255;
      int head = cr >> 5, d = cr & 31;
      float bq = bqkv[c];
      size_t bh = (size_t)(b*NHD + head);
      #pragma unroll
      for (int r = 0; r < 4; ++r)
        dst[(bh*NN + nbase + r)*DHD + d] = f2bf(acc[nt][r] + bq);
    }
  } else {
    __syncthreads();
    unsigned short (*vt)[20] = (unsigned short(*)[20])&xs[0][0];  // [128][20]
    #pragma unroll
    for (int nt = 0; nt < 2; ++nt) {
      int cr = cw + nt*16 + lo;
      float bq = bqkv[n0 + cr];
      union { unsigned short u[4]; unsigned wd[2]; } pk;
      #pragma unroll
      for (int r = 0; r < 4; ++r) pk.u[r] = f2bf(acc[nt][r] + bq);
      int col = hi*4;
      *(unsigned*)&vt[cr][col]     = pk.wd[0];
      *(unsigned*)&vt[cr][col + 2] = pk.wd[1];
    }
    __syncthreads();
    int nn0 = m0 & 1023;
    int row = tid >> 1, ch = tid & 1;
    int cr256 = (n0 - 512) + row;
    int head = cr256 >> 5, d = cr256 & 31;
    *(bf16x8*)&vtws[((size_t)(b*NHD + head)*DHD + d)*NN + nn0 + ch*8] =
        *(const bf16x8*)&vt[row][ch*8];
  }
}

// ------- Kernel 3: swapped-operand MFMA flash attention, no-max softmax -----
// r21 base + T5 s_setprio(1) around both MFMA clusters (isolated A/B).
__global__ __launch_bounds__(256, 4) void attn_kernel(
    const unsigned short* __restrict__ Q, const unsigned short* __restrict__ K,
    const unsigned short* __restrict__ Vt, const float* __restrict__ coord,
    const int* __restrict__ mask, const unsigned short* __restrict__ tblb,
    unsigned short* __restrict__ pO, float* __restrict__ pL)
{
  __shared__ unsigned short tableL[TBSX];          // 7184 B (bf16, log2 units)
  __shared__ unsigned short Klds[2][64][40];       // 10 KB (dbuf)
  __shared__ unsigned short Vtlds[2][32][72];      //  9 KB (dbuf)
  __shared__ __align__(16) float ckL[NN/NSPL];     //  2 KB (pre-scaled coords)

  int tid = threadIdx.x, lane = tid & 63, w = tid >> 6;
  int bh = blockIdx.y, half = blockIdx.z;
  int b = bh >> 3, head = bh & 7;
  int qbase = blockIdx.x * 64 + w * 16;
  int lo = lane & 15, hi = lane >> 4;

  {
    const uint4* src = (const uint4*)(tblb + head*TBSX);
    uint4* dst = (uint4*)tableL;
    for (int i = tid; i < TBSX/8; i += 256) dst[i] = src[i];
  }

  bf16x8 qf = *(const bf16x8*)&Q[((size_t)bh*NN + qbase + lo)*DHD + hi*8];
  // i0 = (int)(ck*1024 + (1024.5 - cq*1024))
  float qoff2 = fmaf(coord[b*NN + qbase + lo], -(float)TI2*0.5f,
                     (float)TI2*0.5f + 0.5f);

  float l = 0.f;
  f32x4 oacc[2];
  oacc[0] = (f32x4){0.f,0.f,0.f,0.f};
  oacc[1] = (f32x4){0.f,0.f,0.f,0.f};
  const float scale2 = 0.17677669529663689f * LOG2E;

  int kt0 = half * (NN/NSPL);
  int sr = tid >> 2, ss = tid & 3;                 // K stage map
  int vr = tid >> 3, vs = tid & 7;                 // V stage map
  {
    #pragma unroll
    for (int i = 0; i < (NN/NSPL)/256; ++i) {
      int idx = i*256 + tid;
      // fold mask at stage time; pre-scale by 1024 (exact pow2 multiply)
      ckL[idx] = (mask[b*NN + kt0 + idx] ? coord[b*NN + kt0 + idx] : 2.5f)
                 * ((float)TI2*0.5f);
    }
    *(bf16x8*)&Klds[0][sr][ss*8] =
        *(const bf16x8*)&K[((size_t)bh*NN + kt0 + sr)*DHD + ss*8];
    *(bf16x8*)&Vtlds[0][vr][vs*8] =
        *(const bf16x8*)&Vt[((size_t)bh*DHD + vr)*NN + kt0 + vs*8];
  }
  __syncthreads();

  for (int t = 0; t < NN/NSPL/64; ++t) {
    int kt = kt0 + t*64;
    int cur = t & 1;
    bf16x8 kn, vn;
    if (t < NN/NSPL/64 - 1) {
      kn = *(const bf16x8*)&K[((size_t)bh*NN + kt + 64 + sr)*DHD + ss*8];
      vn = *(const bf16x8*)&Vt[((size_t)bh*DHD + vr)*NN + kt + 64 + vs*8];
    }
    // per-lane pre-scaled coords: LDS broadcast reads
    float ck[4][4];
    #pragma unroll
    for (int nt = 0; nt < 4; ++nt) {
      float4 c4 = *(const float4*)&ckL[t*64 + nt*16 + hi*4];
      ck[nt][0] = c4.x; ck[nt][1] = c4.y; ck[nt][2] = c4.z; ck[nt][3] = c4.w;
    }

    // S^T = K . Q^T
    f32x4 z = {0.f,0.f,0.f,0.f};
    f32x4 sacc[4];
    __builtin_amdgcn_s_setprio(1);
    #pragma unroll
    for (int nt = 0; nt < 4; ++nt) {
      bf16x8 kf = *(const bf16x8*)&Klds[cur][nt*16 + lo][hi*8];
      sacc[nt] = __builtin_amdgcn_mfma_f32_16x16x32_bf16(kf, qf, z, 0, 0, 0);
    }
    __builtin_amdgcn_s_setprio(0);

    // bias+mask lookup (nearest, log2 domain), then P = 2^s directly
    bf16x4 pfrag[4];
    #pragma unroll
    for (int nt = 0; nt < 4; ++nt) {
      float p[4];
      #pragma unroll
      for (int r = 0; r < 4; ++r) {
        int i0 = (int)(ck[nt][r] + qoff2);
        float s = fmaf(sacc[nt][r], scale2, bf2f(tableL[i0]));
        p[r] = __builtin_amdgcn_exp2f(s);
      }
      l += (p[0] + p[1]) + (p[2] + p[3]);
      union { bf16x4 v; unsigned short u[4]; } pk;
      pk.u[0] = f2bf(p[0]); pk.u[1] = f2bf(p[1]);
      pk.u[2] = f2bf(p[2]); pk.u[3] = f2bf(p[3]);
      pfrag[nt] = pk.v;
    }

    // O^T += V^T . P^T
    __builtin_amdgcn_s_setprio(1);
    #pragma unroll
    for (int nt = 0; nt < 4; ++nt) {
      #pragma unroll
      for (int n2 = 0; n2 < 2; ++n2) {
        bf16x4 vf = *(const bf16x4*)&Vtlds[cur][n2*16 + lo][nt*16 + hi*4];
        pv_mfma(oacc[n2], vf, pfrag[nt]);
      }
    }
    __builtin_amdgcn_s_setprio(0);

    if (t < NN/NSPL/64 - 1) {
      *(bf16x8*)&Klds[cur^1][sr][ss*8] = kn;
      *(bf16x8*)&Vtlds[cur^1][vr][vs*8] = vn;
    }
    __syncthreads();
  }

  // epilogue: l across hi-lanes; store unnormalized O^T (bf16) + l
  l += __shfl_xor(l, 16);
  l += __shfl_xor(l, 32);
  size_t base = ((size_t)(half*BB*NHD + bh)*NN + qbase + lo);
  #pragma unroll
  for (int n2 = 0; n2 < 2; ++n2) {
    union { bf16x4 v; unsigned short u[4]; } ov;
    ov.u[0] = f2bf(oacc[n2][0]); ov.u[1] = f2bf(oacc[n2][1]);
    ov.u[2] = f2bf(oacc[n2][2]); ov.u[3] = f2bf(oacc[n2][3]);
    *(bf16x4*)&pO[base*DHD + n2*16 + hi*4] = ov.v;
  }
  if (hi == 0) pL[base] = l;
}

// ---- Kernel 4: fused combine + MFMA proj GEMM + bias + residual ------------
// No-max softmax => merge is a pure add-and-scale: O = (O0 + O1)/(l0 + l1).
__global__ __launch_bounds__(256) void proj_mm_kernel(
    const unsigned short* __restrict__ pO, const float* __restrict__ pL,
    const unsigned short* __restrict__ Wpt, const float* __restrict__ bp,
    const float* __restrict__ h, float* __restrict__ out)
{
  __shared__ unsigned short alds[32][264];   // merged A-tile, +8 pad
  int tid = threadIdx.x;
  int m0 = blockIdx.x * 32, n0 = blockIdx.y * 32;

  // merge rows m0..m0+31: thread -> (row r, head q)
  {
    int r = tid >> 3, q = tid & 7;
    int g = m0 + r, b = g >> 10, n = g & 1023;
    int bhh = b*NHD + q;
    float l0 = pL[(size_t)bhh*NN + n];
    float l1 = pL[(size_t)(BB*NHD)*NN + (size_t)bhh*NN + n];
    float inv = 1.0f / (l0 + l1);
    const bf16x8* p0 = (const bf16x8*)&pO[((size_t)bhh*NN + n)*DHD];
    const bf16x8* p1 = (const bf16x8*)&pO[(((size_t)(BB*NHD) + bhh)*NN + n)*DHD];
    #pragma unroll
    for (int j = 0; j < 4; ++j) {
      union { bf16x8 v; unsigned short u[8]; } a, c, o;
      a.v = p0[j]; c.v = p1[j];
      #pragma unroll
      for (int e = 0; e < 8; ++e)
        o.u[e] = f2bf((bf2f(a.u[e]) + bf2f(c.u[e])) * inv);
      *(bf16x8*)&alds[r][q*32 + j*8] = o.v;
    }
  }
  __syncthreads();

  // GEMM: wave w -> rows m0+(w&1)*16, cols n0+(w>>1)*16
  int lane = tid & 63, w = tid >> 6;
  int lo = lane & 15, hi = lane >> 4;
  int mw = (w & 1) * 16;
  int nw = n0 + (w >> 1) * 16;
  f32x4 acc = (f32x4){0.f,0.f,0.f,0.f};

  #pragma unroll
  for (int ks = 0; ks < 8; ++ks) {
    bf16x8 af = *(const bf16x8*)&alds[mw + lo][ks*32 + hi*8];
    bf16x8 bf = *(const bf16x8*)&Wpt[(size_t)(nw + lo)*256 + ks*32 + hi*8];
    acc = __builtin_amdgcn_mfma_f32_16x16x32_bf16(af, bf, acc, 0, 0, 0);
  }

  int c = nw + lo;
  float bpv = bp[c];
  #pragma unroll
  for (int r = 0; r < 4; ++r) {
    size_t o = (size_t)(m0 + mw + hi*4 + r)*HIDD + c;
    out[o] = h[o] + acc[r] + bpv;
  }
}

// ---------------- launch ----------------------------------------------------
extern "C" void kernel_launch(void* const* d_in, const int* in_sizes, int n_in,
                              void* d_out, int out_size, void* d_ws, size_t ws_size,
                              hipStream_t stream)
{
  const float* h     = (const float*)d_in[0];
  const float* coord = (const float*)d_in[1];
  const int*   mask  = (const int*)  d_in[2];
  const float* Wqkv  = (const float*)d_in[3];
  const float* bqkv  = (const float*)d_in[4];
  const float* Wproj = (const float*)d_in[5];
  const float* bproj = (const float*)d_in[6];
  const float* gamma = (const float*)d_in[7];
  const float* beta  = (const float*)d_in[8];
  const float* Wb1   = (const float*)d_in[9];
  const float* bb1   = (const float*)d_in[10];
  const float* Wb2   = (const float*)d_in[11];
  const float* bb2   = (const float*)d_in[12];
  const float* Wb3   = (const float*)d_in[13];
  const float* bb3   = (const float*)d_in[14];
  float* out = (float*)d_out;

  unsigned short* tblb = (unsigned short*)d_ws;         // 8*3592 ushorts (57472 B)
  float* pL = (float*)(tblb + NHD*TBSX);                // 64K floats (256 KB)
  unsigned short* wtq  = (unsigned short*)(pL + (size_t)NSPL*BB*NHD*NN);
  unsigned short* wtp  = wtq + 768*256;
  unsigned short* qws  = wtp + 256*256;
  unsigned short* kws  = qws + (size_t)BB*NHD*NN*DHD;   // 1 Mi elems each
  unsigned short* vtws = kws + (size_t)BB*NHD*NN*DHD;
  unsigned short* pO   = vtws + (size_t)BB*NHD*NN*DHD;  // 2 Mi elems (bf16)

  prep_kernel<<<dim3(1545), dim3(256), 0, stream>>>(
      Wb1, bb1, Wb2, bb2, Wb3, bb3, Wqkv, Wproj, tblb, wtq, wtp);
  ln_qkv_mm_kernel<<<dim3(BB*NN/16, 6), dim3(256), 0, stream>>>(
      h, gamma, beta, wtq, bqkv, qws, kws, vtws);
  attn_kernel<<<dim3(NN/64, BB*NHD, NSPL), dim3(256), 0, stream>>>(
      qws, kws, vtws, coord, mask, tblb, pO, pL);
  proj_mm_kernel<<<dim3(BB*NN/32, HIDD/32), dim3(256), 0, stream>>>(
      pO, pL, wtp, bproj, h, out);
}